// Round 3
// baseline (437.277 us; speedup 1.0000x reference)
//
#include <hip/hip_runtime.h>
#include <hip/hip_bf16.h>
#include <stdint.h>
#include <stddef.h>

typedef __hip_bfloat16 bf16_t;
typedef __attribute__((ext_vector_type(8))) short short8;
typedef __attribute__((ext_vector_type(4))) short short4v;
typedef __attribute__((ext_vector_type(4))) float floatx4;

#define EMBED 1024
#define NHEAD 16
#define HDIM  64
#define BATCH 2
#define SEQ   2048
#define MTOT  (BATCH*SEQ)
#define NEG_INF (-1e30f)

#define MFMA16(a,b,c) __builtin_amdgcn_mfma_f32_16x16x32_bf16(a,b,c,0,0,0)

static __device__ __forceinline__ short bf16_bits(float x) {
    return __builtin_bit_cast(short, __float2bfloat16(x));
}

// async global->LDS, 16B per lane; lds ptr must be wave-uniform (HW: base + lane*16)
static __device__ __forceinline__ void async_ld16(const bf16_t* g, short* l) {
    __builtin_amdgcn_global_load_lds(
        (const __attribute__((address_space(1))) void*)g,
        (__attribute__((address_space(3))) void*)l,
        16, 0, 0);
}

static __device__ __forceinline__ void store_out(float* p, float v)  { *p = v; }
static __device__ __forceinline__ void store_out(bf16_t* p, float v) { *p = __float2bfloat16(v); }

// fp32 -> bf16 (RTNE) for q,k,v (4M each) and Wq,Wk,Wv,Wo (1M each). grid.y selects tensor.
__global__ __launch_bounds__(256)
void cvt_all(const float* __restrict__ q, const float* __restrict__ k, const float* __restrict__ v,
             const float* __restrict__ wq, const float* __restrict__ wk,
             const float* __restrict__ wv, const float* __restrict__ wo,
             bf16_t* __restrict__ Qx, bf16_t* __restrict__ Kx, bf16_t* __restrict__ Vx,
             bf16_t* __restrict__ Wqb, bf16_t* __restrict__ Wkb,
             bf16_t* __restrict__ Wvb, bf16_t* __restrict__ Wob)
{
    const float* s; bf16_t* d; int n;
    switch (blockIdx.y) {
        case 0:  s = q;  d = Qx;  n = MTOT * EMBED;  break;
        case 1:  s = k;  d = Kx;  n = MTOT * EMBED;  break;
        case 2:  s = v;  d = Vx;  n = MTOT * EMBED;  break;
        case 3:  s = wq; d = Wqb; n = EMBED * EMBED; break;
        case 4:  s = wk; d = Wkb; n = EMBED * EMBED; break;
        case 5:  s = wv; d = Wvb; n = EMBED * EMBED; break;
        default: s = wo; d = Wob; n = EMBED * EMBED; break;
    }
    const int i4 = (int)blockIdx.x * 256 + (int)threadIdx.x;   // float4 index
    if (i4 * 4 < n) {
        const float4 f = ((const float4*)s)[i4];
        short4v o;
        o[0] = bf16_bits(f.x); o[1] = bf16_bits(f.y);
        o[2] = bf16_bits(f.z); o[3] = bf16_bits(f.w);
        ((short4v*)d)[i4] = o;
    }
}

// C[M,N] = A[M,K] @ W[N,K]^T + bias, bf16 in, fp32 accumulate, OutT out.
// M=4096, N=K=1024 fixed. 128x128 tile, BK=32, 256 thr (4 waves 2x2). m97 structure.
template <typename OutT>
static __device__ __forceinline__ void gemm_tile_128(
    const bf16_t* __restrict__ A, const bf16_t* __restrict__ W,
    const float* __restrict__ bias, OutT* __restrict__ C)
{
    const int N = 1024, K = 1024;
    __shared__ alignas(16) short As[128*32];
    __shared__ alignas(16) short Bs[128*32];

    const int tid  = threadIdx.x;
    const int wave = tid >> 6;
    const int lane = tid & 63;
    const int nbn = N >> 7;                 // 8
    const int bm = (int)blockIdx.x / nbn;
    const int bn = (int)blockIdx.x % nbn;
    const int m0 = bm << 7, n0 = bn << 7;

    const int wm = ((wave >> 1) & 1) << 6;  // 0 / 64
    const int wn = (wave & 1) << 6;

    floatx4 acc[4][4] = {};

    // staging: wave stages 32 rows of A-tile and 32 rows of B-tile (2 instrs of 16 rows each)
    const int srow = (wave << 5) + (lane >> 2);   // row within tile
    const int scol = (lane & 3) << 3;             // element col: 0,8,16,24 (16B chunks)
    const bf16_t* gA = A + (size_t)(m0 + srow) * K + scol;
    const bf16_t* gB = W + (size_t)(n0 + srow) * K + scol;
    short* lA0 = &As[(wave << 10)];
    short* lA1 = &As[(wave << 10) + 512];
    short* lB0 = &Bs[(wave << 10)];
    short* lB1 = &Bs[(wave << 10) + 512];

    const int fr = lane & 15;
    const int fk = (lane >> 4) << 3;

    for (int k0 = 0; k0 < K; k0 += 32) {
        __syncthreads();                      // previous iter's readers done
        async_ld16(gA,                  lA0);
        async_ld16(gA + (size_t)16 * K, lA1);
        async_ld16(gB,                  lB0);
        async_ld16(gB + (size_t)16 * K, lB1);
        gA += 32; gB += 32;
        __syncthreads();                      // drains vmcnt before barrier (m97-verified)

        short8 af[4], bfr[4];
        #pragma unroll
        for (int i = 0; i < 4; ++i)
            af[i] = *(const short8*)&As[(wm + (i << 4) + fr) * 32 + fk];
        #pragma unroll
        for (int j = 0; j < 4; ++j)
            bfr[j] = *(const short8*)&Bs[(wn + (j << 4) + fr) * 32 + fk];
        #pragma unroll
        for (int i = 0; i < 4; ++i)
            #pragma unroll
            for (int j = 0; j < 4; ++j)
                acc[i][j] = MFMA16(af[i], bfr[j], acc[i][j]);
    }

    // epilogue: C/D layout col=lane&15, row=quad*4+r
    const int q4 = (lane >> 4) << 2;
    #pragma unroll
    for (int j = 0; j < 4; ++j) {
        const int n = n0 + wn + (j << 4) + fr;
        const float bv = bias[n];
        #pragma unroll
        for (int i = 0; i < 4; ++i) {
            const int mb = m0 + wm + (i << 4) + q4;
            #pragma unroll
            for (int r = 0; r < 4; ++r)
                store_out(&C[(size_t)(mb + r) * N + n], acc[i][j][r] + bv);
        }
    }
}

__global__ __launch_bounds__(256)
void qkv_proj(const bf16_t* __restrict__ xq, const bf16_t* __restrict__ xk,
              const bf16_t* __restrict__ xv,
              const bf16_t* __restrict__ Wq, const bf16_t* __restrict__ Wk,
              const bf16_t* __restrict__ Wv,
              const float* __restrict__ bq, const float* __restrict__ bk,
              const float* __restrict__ bv,
              bf16_t* __restrict__ Qp, bf16_t* __restrict__ Kp, bf16_t* __restrict__ Vp)
{
    const bf16_t* A; const bf16_t* W; const float* b; bf16_t* C;
    if (blockIdx.z == 0)      { A = xq; W = Wq; b = bq; C = Qp; }
    else if (blockIdx.z == 1) { A = xk; W = Wk; b = bk; C = Kp; }
    else                      { A = xv; W = Wv; b = bv; C = Vp; }
    gemm_tile_128(A, W, b, C);
}

__global__ __launch_bounds__(256)
void out_proj(const bf16_t* __restrict__ AO, const bf16_t* __restrict__ Wo,
              const float* __restrict__ bo, float* __restrict__ out)
{
    gemm_tile_128(AO, Wo, bo, out);
}

// Flash attention, causal. One wave = 16 q rows. Block = 4 waves = 64 q rows of one (b,h).
// Q/K/V in [B*S, H*D] row-major (head h at col h*64). KV trip count is BLOCK-uniform
// (waves 0/1 run <=1 fully-masked extra chunk, a no-op: p=0, alpha=1), so __syncthreads()
// between P-write and P-read is legal.
__global__ __launch_bounds__(256)
void attn_causal(const bf16_t* __restrict__ Qp, const bf16_t* __restrict__ Kp,
                 const bf16_t* __restrict__ Vp, bf16_t* __restrict__ AO)
{
    __shared__ alignas(16) short Pbuf[4][16 * 32];   // per-wave P tile [16 q][32 kv]

    const int tid  = threadIdx.x;
    const int wave = tid >> 6;
    const int lane = tid & 63;
    const int qb = (int)blockIdx.x & 31;          // S/64 = 32
    const int h  = ((int)blockIdx.x >> 5) & 15;
    const int b  = (int)blockIdx.x >> 9;
    const int q0 = (qb << 6) + (wave << 4);

    const int fr   = lane & 15;
    const int quad = lane >> 4;
    const int fk   = quad << 3;

    // Q A-frags, in registers: A[m=fr][k=fk..fk+8] for d in [0,32) and [32,64)
    const bf16_t* Qrow = Qp + (size_t)(b * SEQ + q0 + fr) * EMBED + h * HDIM;
    const short8 aq0 = *(const short8*)(Qrow + fk);
    const short8 aq1 = *(const short8*)(Qrow + 32 + fk);

    floatx4 o[4] = {};          // O accumulator, C-layout per 16-wide d-tile
    float mrow[4], lrow[4];
    #pragma unroll
    for (int r = 0; r < 4; ++r) { mrow[r] = NEG_INF; lrow[r] = 0.f; }

    const int nchunks = 2 * qb + 2;               // block-uniform causal bound
    for (int c = 0; c < nchunks; ++c) {
        const int kv0 = c << 5;

        // K B-frags: lane holds B[k=d=fk+j][n=kv=fr] = K[kv0+(sub*16)+fr][d]
        const bf16_t* Krow0 = Kp + (size_t)(b * SEQ + kv0 + fr) * EMBED + h * HDIM;
        const bf16_t* Krow1 = Krow0 + (size_t)16 * EMBED;
        const short8 k00 = *(const short8*)(Krow0 + fk);
        const short8 k01 = *(const short8*)(Krow0 + 32 + fk);
        const short8 k10 = *(const short8*)(Krow1 + fk);
        const short8 k11 = *(const short8*)(Krow1 + 32 + fk);

        floatx4 s0 = {}, s1 = {};
        s0 = MFMA16(aq0, k00, s0);
        s0 = MFMA16(aq1, k01, s0);
        s1 = MFMA16(aq0, k10, s1);
        s1 = MFMA16(aq1, k11, s1);

        // scale + causal mask (C-layout: row = q0+quad*4+r, col = kv0 + [0|16] + fr)
        float p0[4], p1[4], rmax[4];
        const bool needmask = (kv0 + 32 > q0);
        #pragma unroll
        for (int r = 0; r < 4; ++r) {
            const int grow = q0 + (quad << 2) + r;
            float v0 = s0[r] * 0.125f;
            float v1 = s1[r] * 0.125f;
            if (needmask) {
                if (kv0 + fr > grow)      v0 = NEG_INF;
                if (kv0 + 16 + fr > grow) v1 = NEG_INF;
            }
            p0[r] = v0; p1[r] = v1;
            rmax[r] = fmaxf(v0, v1);
        }
        // row reduction: each row lives in one quad's 16 lanes; xor 1/2/4/8 stays in-quad
        #pragma unroll
        for (int off = 1; off < 16; off <<= 1)
            #pragma unroll
            for (int r = 0; r < 4; ++r)
                rmax[r] = fmaxf(rmax[r], __shfl_xor(rmax[r], off, 64));

        float alpha[4], rsum[4];
        #pragma unroll
        for (int r = 0; r < 4; ++r) {
            const float mnew = fmaxf(mrow[r], rmax[r]);
            alpha[r] = __expf(mrow[r] - mnew);
            mrow[r] = mnew;
            p0[r] = __expf(p0[r] - mnew);
            p1[r] = __expf(p1[r] - mnew);
            rsum[r] = p0[r] + p1[r];
        }
        #pragma unroll
        for (int off = 1; off < 16; off <<= 1)
            #pragma unroll
            for (int r = 0; r < 4; ++r)
                rsum[r] += __shfl_xor(rsum[r], off, 64);
        #pragma unroll
        for (int r = 0; r < 4; ++r) lrow[r] = lrow[r] * alpha[r] + rsum[r];
        #pragma unroll
        for (int t = 0; t < 4; ++t)
            #pragma unroll
            for (int r = 0; r < 4; ++r) o[t][r] *= alpha[r];

        // P: C-layout -> LDS -> A-layout (m120-verified transform)
        short* Pw = &Pbuf[wave][0];
        #pragma unroll
        for (int r = 0; r < 4; ++r) {
            Pw[((quad << 2) + r) * 32 + fr]      = bf16_bits(p0[r]);
            Pw[((quad << 2) + r) * 32 + 16 + fr] = bf16_bits(p1[r]);
        }
        __syncthreads();   // ds_write -> ds_read ordering (legal: uniform trip count)
        const short8 pa = *(const short8*)&Pw[fr * 32 + fk];

        // PV: lane holds B[k=kv=fk+j][n=d=t*16+fr] = V[kv0+fk+j][h*64+t*16+fr]
        #pragma unroll
        for (int t = 0; t < 4; ++t) {
            const bf16_t* Vb = Vp + (size_t)(b * SEQ + kv0 + fk) * EMBED + h * HDIM + (t << 4) + fr;
            short8 vf;
            #pragma unroll
            for (int j = 0; j < 8; ++j)
                vf[j] = *(const short*)(Vb + (size_t)j * EMBED);
            o[t] = MFMA16(pa, vf, o[t]);
        }
        __syncthreads();   // P-read done in all waves before next iter's P-write
    }

    // normalize + store (C-layout)
    #pragma unroll
    for (int t = 0; t < 4; ++t) {
        #pragma unroll
        for (int r = 0; r < 4; ++r) {
            const int grow = q0 + (quad << 2) + r;
            AO[(size_t)(b * SEQ + grow) * EMBED + h * HDIM + (t << 4) + fr] =
                __float2bfloat16(o[t][r] / lrow[r]);
        }
    }
}

extern "C" void kernel_launch(void* const* d_in, const int* in_sizes, int n_in,
                              void* d_out, int out_size, void* d_ws, size_t ws_size,
                              hipStream_t stream)
{
    (void)in_sizes; (void)n_in; (void)out_size; (void)ws_size;
    // Reference dtypes: ALL float32 (jnp.float32). Internal compute: bf16 MFMA.
    const float* q  = (const float*)d_in[0];
    const float* k  = (const float*)d_in[1];
    const float* v  = (const float*)d_in[2];
    const float* Wq = (const float*)d_in[3];
    const float* bq = (const float*)d_in[4];
    const float* Wk = (const float*)d_in[5];
    const float* bk = (const float*)d_in[6];
    const float* Wv = (const float*)d_in[7];
    const float* bv = (const float*)d_in[8];
    const float* Wo = (const float*)d_in[9];
    const float* bo = (const float*)d_in[10];
    // d_in[11] = attn_mask: fixed causal tril, handled analytically.

    const size_t NX = (size_t)MTOT * EMBED;   // 4M
    const size_t NW = (size_t)EMBED * EMBED;  // 1M
    bf16_t* Qx  = (bf16_t*)d_ws;
    bf16_t* Kx  = Qx  + NX;
    bf16_t* Vx  = Kx  + NX;
    bf16_t* Wqb = Vx  + NX;
    bf16_t* Wkb = Wqb + NW;
    bf16_t* Wvb = Wkb + NW;
    bf16_t* Wob = Wvb + NW;
    bf16_t* Qp  = Wob + NW;
    bf16_t* Kp  = Qp  + NX;
    bf16_t* Vp  = Kp  + NX;
    bf16_t* AO  = Vp  + NX;   // total 32M bf16 = 64 MB

    dim3 blk(256);
    cvt_all<<<dim3(4096, 7), blk, 0, stream>>>(q, k, v, Wq, Wk, Wv, Wo,
                                               Qx, Kx, Vx, Wqb, Wkb, Wvb, Wob);
    qkv_proj<<<dim3(256, 1, 3), blk, 0, stream>>>(Qx, Kx, Vx, Wqb, Wkb, Wvb,
                                                  bq, bk, bv, Qp, Kp, Vp);
    attn_causal<<<dim3(BATCH * NHEAD * (SEQ / 64)), blk, 0, stream>>>(Qp, Kp, Vp, AO);
    out_proj<<<dim3(256), blk, 0, stream>>>(AO, Wob, bo, (float*)d_out);
}

// Round 4
// 329.637 us; speedup vs baseline: 1.3265x; 1.3265x over previous
//
#include <hip/hip_runtime.h>
#include <hip/hip_bf16.h>
#include <stdint.h>
#include <stddef.h>

typedef __hip_bfloat16 bf16_t;
typedef __attribute__((ext_vector_type(8))) short short8;
typedef __attribute__((ext_vector_type(4))) short short4v;
typedef __attribute__((ext_vector_type(4))) float floatx4;

#define EMBED 1024
#define NHEAD 16
#define HDIM  64
#define BATCH 2
#define SEQ   2048
#define MTOT  (BATCH*SEQ)
#define NEG_INF (-1e30f)

#define MFMA16(a,b,c) __builtin_amdgcn_mfma_f32_16x16x32_bf16(a,b,c,0,0,0)

static __device__ __forceinline__ short bf16_bits(float x) {
    return __builtin_bit_cast(short, __float2bfloat16(x));
}

// async global->LDS, 16B per lane; lds ptr must be wave-uniform (HW: base + lane*16)
static __device__ __forceinline__ void async_ld16(const bf16_t* g, short* l) {
    __builtin_amdgcn_global_load_lds(
        (const __attribute__((address_space(1))) void*)g,
        (__attribute__((address_space(3))) void*)l,
        16, 0, 0);
}

static __device__ __forceinline__ void store_out(float* p, float v)  { *p = v; }
static __device__ __forceinline__ void store_out(bf16_t* p, float v) { *p = __float2bfloat16(v); }

// fp32 -> bf16 (RTNE) for q,k,v (4M each) and Wq,Wk,Wv,Wo (1M each). grid.y selects tensor.
__global__ __launch_bounds__(256)
void cvt_all(const float* __restrict__ q, const float* __restrict__ k, const float* __restrict__ v,
             const float* __restrict__ wq, const float* __restrict__ wk,
             const float* __restrict__ wv, const float* __restrict__ wo,
             bf16_t* __restrict__ Qx, bf16_t* __restrict__ Kx, bf16_t* __restrict__ Vx,
             bf16_t* __restrict__ Wqb, bf16_t* __restrict__ Wkb,
             bf16_t* __restrict__ Wvb, bf16_t* __restrict__ Wob)
{
    const float* s; bf16_t* d; int n;
    switch (blockIdx.y) {
        case 0:  s = q;  d = Qx;  n = MTOT * EMBED;  break;
        case 1:  s = k;  d = Kx;  n = MTOT * EMBED;  break;
        case 2:  s = v;  d = Vx;  n = MTOT * EMBED;  break;
        case 3:  s = wq; d = Wqb; n = EMBED * EMBED; break;
        case 4:  s = wk; d = Wkb; n = EMBED * EMBED; break;
        case 5:  s = wv; d = Wvb; n = EMBED * EMBED; break;
        default: s = wo; d = Wob; n = EMBED * EMBED; break;
    }
    const int i4 = (int)blockIdx.x * 256 + (int)threadIdx.x;   // float4 index
    if (i4 * 4 < n) {
        const float4 f = ((const float4*)s)[i4];
        short4v o;
        o[0] = bf16_bits(f.x); o[1] = bf16_bits(f.y);
        o[2] = bf16_bits(f.z); o[3] = bf16_bits(f.w);
        ((short4v*)d)[i4] = o;
    }
}

// C[M,N] = A[M,K] @ W[N,K]^T + bias, bf16 in, fp32 accumulate.
// M=4096, N=K=1024 fixed. 128x128 tile, BK=32, 256 thr (4 waves 2x2). m97 structure.
// VT=true: write output transposed per-batch as Ct[b*1024 + n][s] (for V: [b, d_global, s]).
template <typename OutT, bool VT>
static __device__ __forceinline__ void gemm_tile_128(
    const bf16_t* __restrict__ A, const bf16_t* __restrict__ W,
    const float* __restrict__ bias, OutT* __restrict__ C)
{
    const int N = 1024, K = 1024;
    __shared__ alignas(16) short As[128*32];
    __shared__ alignas(16) short Bs[128*32];

    const int tid  = threadIdx.x;
    const int wave = tid >> 6;
    const int lane = tid & 63;
    const int nbn = N >> 7;                 // 8
    const int bm = (int)blockIdx.x / nbn;
    const int bn = (int)blockIdx.x % nbn;
    const int m0 = bm << 7, n0 = bn << 7;

    const int wm = ((wave >> 1) & 1) << 6;  // 0 / 64
    const int wn = (wave & 1) << 6;

    floatx4 acc[4][4] = {};

    const int srow = (wave << 5) + (lane >> 2);   // staging row within tile
    const int scol = (lane & 3) << 3;             // element col: 0,8,16,24
    const bf16_t* gA = A + (size_t)(m0 + srow) * K + scol;
    const bf16_t* gB = W + (size_t)(n0 + srow) * K + scol;
    short* lA0 = &As[(wave << 10)];
    short* lA1 = &As[(wave << 10) + 512];
    short* lB0 = &Bs[(wave << 10)];
    short* lB1 = &Bs[(wave << 10) + 512];

    const int fr = lane & 15;
    const int fk = (lane >> 4) << 3;

    for (int k0 = 0; k0 < K; k0 += 32) {
        __syncthreads();
        async_ld16(gA,                  lA0);
        async_ld16(gA + (size_t)16 * K, lA1);
        async_ld16(gB,                  lB0);
        async_ld16(gB + (size_t)16 * K, lB1);
        gA += 32; gB += 32;
        __syncthreads();                      // drains vmcnt before barrier (m97-verified)

        short8 af[4], bfr[4];
        #pragma unroll
        for (int i = 0; i < 4; ++i)
            af[i] = *(const short8*)&As[(wm + (i << 4) + fr) * 32 + fk];
        #pragma unroll
        for (int j = 0; j < 4; ++j)
            bfr[j] = *(const short8*)&Bs[(wn + (j << 4) + fr) * 32 + fk];
        #pragma unroll
        for (int i = 0; i < 4; ++i)
            #pragma unroll
            for (int j = 0; j < 4; ++j)
                acc[i][j] = MFMA16(af[i], bfr[j], acc[i][j]);
    }

    // epilogue: C/D layout col=lane&15, row=quad*4+r
    const int q4 = (lane >> 4) << 2;
    #pragma unroll
    for (int j = 0; j < 4; ++j) {
        const int n = n0 + wn + (j << 4) + fr;
        const float bv = bias[n];
        #pragma unroll
        for (int i = 0; i < 4; ++i) {
            const int mb = m0 + wm + (i << 4) + q4;
            if (VT) {
                // transposed store: Ct[(b*1024 + n)][s], s = mb&2047 .. +3 contiguous (8B)
                const int bb = mb >> 11, ss = mb & 2047;
                short4v pk;
                #pragma unroll
                for (int r = 0; r < 4; ++r)
                    pk[r] = bf16_bits(acc[i][j][r] + bv);
                *(short4v*)((bf16_t*)C + ((size_t)(bb * 1024 + n) << 11) + ss) = pk;
            } else {
                #pragma unroll
                for (int r = 0; r < 4; ++r)
                    store_out(&C[(size_t)(mb + r) * N + n], acc[i][j][r] + bv);
            }
        }
    }
}

__global__ __launch_bounds__(256)
void qkv_proj(const bf16_t* __restrict__ xq, const bf16_t* __restrict__ xk,
              const bf16_t* __restrict__ xv,
              const bf16_t* __restrict__ Wq, const bf16_t* __restrict__ Wk,
              const bf16_t* __restrict__ Wv,
              const float* __restrict__ bq, const float* __restrict__ bk,
              const float* __restrict__ bv,
              bf16_t* __restrict__ Qp, bf16_t* __restrict__ Kp, bf16_t* __restrict__ Vtp)
{
    if (blockIdx.z == 0)      gemm_tile_128<bf16_t, false>(xq, Wq, bq, Qp);
    else if (blockIdx.z == 1) gemm_tile_128<bf16_t, false>(xk, Wk, bk, Kp);
    else                      gemm_tile_128<bf16_t, true >(xv, Wv, bv, Vtp);
}

__global__ __launch_bounds__(256)
void out_proj(const bf16_t* __restrict__ AO, const bf16_t* __restrict__ Wo,
              const float* __restrict__ bo, float* __restrict__ out)
{
    gemm_tile_128<float, false>(AO, Wo, bo, out);
}

// Flash attention, causal, S^T formulation: D = K·Q^T puts one q-row per lane
// (q = lane&15), making softmax state scalar and the P transform wave-local.
// No barriers; waves independent. Wave w of block g takes q-tile {g, g+32, 95-g, 127-g}
// -> every block has identical total work (254 chunk-iters).
// Vt layout: Vt[(b*1024 + h*64 + d)][s] (written by qkv_proj VT epilogue).
__global__ __launch_bounds__(256)
void attn_causal(const bf16_t* __restrict__ Qp, const bf16_t* __restrict__ Kp,
                 const bf16_t* __restrict__ Vt, bf16_t* __restrict__ AO)
{
    __shared__ alignas(16) short Pbuf[4][16 * 32];   // per-wave P^T->A staging, 1KB each

    const int tid  = threadIdx.x;
    const int wave = tid >> 6;
    const int lane = tid & 63;
    const int g  = (int)blockIdx.x & 31;
    const int bh = (int)blockIdx.x >> 5;          // 0..31
    const int b  = bh >> 4, h = bh & 15;
    const int t4 = (wave == 0) ? g : (wave == 1) ? (32 + g) : (wave == 2) ? (95 - g) : (127 - g);
    const int q0 = t4 << 4;

    const int fr   = lane & 15;
    const int quad = lane >> 4;
    const int fk   = quad << 3;

    // Q B-frags (B[k=d][n=q]): lane holds Q[q0+fr][fk+j] (+32)
    const bf16_t* Qrow = Qp + (size_t)(b * SEQ + q0 + fr) * EMBED + h * HDIM;
    const short8 aq0 = *(const short8*)(Qrow + fk);
    const short8 aq1 = *(const short8*)(Qrow + 32 + fk);

    const bf16_t* Kbase = Kp + (size_t)(b * SEQ) * EMBED + h * HDIM;
    const bf16_t* Vbase = Vt + ((size_t)(b * 1024 + h * HDIM) << 11);

    floatx4 o[4] = {};            // O[q=quad*4+r][d=t*16+fr]
    float m = NEG_INF, l = 0.f;   // scalar per lane (one q-row per lane)

    short* Pw = &Pbuf[wave][0];
    const int nch = (q0 + 47) >> 5;
    for (int c = 0; c < nch; ++c) {
        const int kv0 = c << 5;

        // K A-frags (A[m=kv][k=d]): lane holds K[kv0+(sub*16)+fr][fk+j]
        const bf16_t* Kr0 = Kbase + (size_t)(kv0 + fr) * EMBED;
        const bf16_t* Kr1 = Kr0 + (size_t)16 * EMBED;
        const short8 k00 = *(const short8*)(Kr0 + fk);
        const short8 k01 = *(const short8*)(Kr0 + 32 + fk);
        const short8 k10 = *(const short8*)(Kr1 + fk);
        const short8 k11 = *(const short8*)(Kr1 + 32 + fk);

        floatx4 s0 = {}, s1 = {};
        s0 = MFMA16(k00, aq0, s0);
        s0 = MFMA16(k01, aq1, s0);
        s1 = MFMA16(k10, aq0, s1);
        s1 = MFMA16(k11, aq1, s1);

        // S^T layout: lane holds S[kv0 + (quad*4+r) (+16)][q0+fr]
        const int q = q0 + fr;
        float v0[4], v1[4];
        float mx = NEG_INF;
        const bool needmask = (kv0 + 32 > q0);
        #pragma unroll
        for (int r = 0; r < 4; ++r) {
            const int kva = kv0 + (quad << 2) + r;
            float a = s0[r] * 0.125f;
            float bsc = s1[r] * 0.125f;
            if (needmask) {
                if (kva > q)      a   = NEG_INF;
                if (kva + 16 > q) bsc = NEG_INF;
            }
            v0[r] = a; v1[r] = bsc;
            mx = fmaxf(mx, fmaxf(a, bsc));
        }
        // row max across quads (lanes fr, fr+16, fr+32, fr+48)
        mx = fmaxf(mx, __shfl_xor(mx, 16, 64));
        mx = fmaxf(mx, __shfl_xor(mx, 32, 64));

        const float mnew = fmaxf(m, mx);
        const float al = __expf(m - mnew);
        m = mnew;
        float ls = 0.f;
        #pragma unroll
        for (int r = 0; r < 4; ++r) {
            v0[r] = __expf(v0[r] - mnew);
            v1[r] = __expf(v1[r] - mnew);
            ls += v0[r] + v1[r];
        }
        ls += __shfl_xor(ls, 16, 64);
        ls += __shfl_xor(ls, 32, 64);
        l = l * al + ls;

        // alpha into O-layout (need alpha[q=quad*4+r]; it lives at lanes fr=quad*4+r)
        float a_o[4];
        #pragma unroll
        for (int r = 0; r < 4; ++r)
            a_o[r] = __shfl(al, (lane & 48) | ((quad << 2) + r), 64);
        #pragma unroll
        for (int t = 0; t < 4; ++t)
            #pragma unroll
            for (int r = 0; r < 4; ++r)
                o[t][r] *= a_o[r];

        // P^T -> wave-local LDS as P[q][kv], then read A-frag (A[m=q][k=kv]).
        short4v w0, w1;
        #pragma unroll
        for (int r = 0; r < 4; ++r) { w0[r] = bf16_bits(v0[r]); w1[r] = bf16_bits(v1[r]); }
        *(short4v*)&Pw[fr * 32 + (quad << 2)]      = w0;
        *(short4v*)&Pw[fr * 32 + 16 + (quad << 2)] = w1;
        __asm__ volatile("" ::: "memory");   // pin compiler order; same-wave DS is in-order in HW
        const short8 pa = *(const short8*)&Pw[fr * 32 + fk];
        __asm__ volatile("" ::: "memory");

        // PV: B-frag (B[k=kv][n=d]) from Vt rows: 16B contiguous per lane
        #pragma unroll
        for (int t = 0; t < 4; ++t) {
            const short8 vf = *(const short8*)(Vbase + (((size_t)((t << 4) + fr)) << 11) + kv0 + fk);
            o[t] = MFMA16(pa, vf, o[t]);
        }
    }

    // l into O-layout, normalize, store
    float l_o[4];
    #pragma unroll
    for (int r = 0; r < 4; ++r)
        l_o[r] = __shfl(l, (lane & 48) | ((quad << 2) + r), 64);
    #pragma unroll
    for (int t = 0; t < 4; ++t) {
        #pragma unroll
        for (int r = 0; r < 4; ++r) {
            const int grow = q0 + (quad << 2) + r;
            AO[(size_t)(b * SEQ + grow) * EMBED + h * HDIM + (t << 4) + fr] =
                __float2bfloat16(o[t][r] / l_o[r]);
        }
    }
}

extern "C" void kernel_launch(void* const* d_in, const int* in_sizes, int n_in,
                              void* d_out, int out_size, void* d_ws, size_t ws_size,
                              hipStream_t stream)
{
    (void)in_sizes; (void)n_in; (void)out_size; (void)ws_size;
    const float* q  = (const float*)d_in[0];
    const float* k  = (const float*)d_in[1];
    const float* v  = (const float*)d_in[2];
    const float* Wq = (const float*)d_in[3];
    const float* bq = (const float*)d_in[4];
    const float* Wk = (const float*)d_in[5];
    const float* bk = (const float*)d_in[6];
    const float* Wv = (const float*)d_in[7];
    const float* bv = (const float*)d_in[8];
    const float* Wo = (const float*)d_in[9];
    const float* bo = (const float*)d_in[10];
    // d_in[11] = attn_mask: fixed causal tril, handled analytically.

    const size_t NX = (size_t)MTOT * EMBED;   // 4M
    const size_t NW = (size_t)EMBED * EMBED;  // 1M
    bf16_t* Qx  = (bf16_t*)d_ws;
    bf16_t* Kx  = Qx  + NX;
    bf16_t* Vx  = Kx  + NX;
    bf16_t* Wqb = Vx  + NX;
    bf16_t* Wkb = Wqb + NW;
    bf16_t* Wvb = Wkb + NW;
    bf16_t* Wob = Wvb + NW;
    bf16_t* Qp  = Wob + NW;
    bf16_t* Kp  = Qp  + NX;
    bf16_t* Vtp = Kp  + NX;   // transposed: [b*1024 + d_global][s]
    bf16_t* AO  = Vtp + NX;   // total 32M bf16 = 64 MB

    dim3 blk(256);
    cvt_all<<<dim3(4096, 7), blk, 0, stream>>>(q, k, v, Wq, Wk, Wv, Wo,
                                               Qx, Kx, Vx, Wqb, Wkb, Wvb, Wob);
    qkv_proj<<<dim3(256, 1, 3), blk, 0, stream>>>(Qx, Kx, Vx, Wqb, Wkb, Wvb,
                                                  bq, bk, bv, Qp, Kp, Vtp);
    attn_causal<<<dim3(1024), blk, 0, stream>>>(Qp, Kp, Vtp, AO);
    out_proj<<<dim3(256), blk, 0, stream>>>(AO, Wob, bo, (float*)d_out);
}